// Round 8
// baseline (1370.389 us; speedup 1.0000x reference)
//
#include <hip/hip_runtime.h>
#include <hip/hip_bf16.h>

#define D_MODEL 1024
#define NHEAD 16
#define DK 64
#define B_ 4
#define S_ 2048
#define ROWS (B_*S_)          // 8192
#define QKV_N (3*D_MODEL)     // 3072

typedef __attribute__((ext_vector_type(4))) float f32x4;
typedef __attribute__((ext_vector_type(8))) short bf16x8;
typedef unsigned short u16;
typedef unsigned int u32;

__device__ __forceinline__ u16 f2bf(float f) {
    union { float f; u32 u; } x; x.f = f;
    u32 r = x.u + 0x7fffu + ((x.u >> 16) & 1u);
    return (u16)(r >> 16);
}
__device__ __forceinline__ float bf2f(u16 h) {
    union { u32 u; float f; } x; x.u = ((u32)h) << 16;
    return x.f;
}
__device__ __forceinline__ u32 pk2bf(float a, float b) {
    union { __hip_bfloat162 h; u32 u; } c;
    c.h = __float22bfloat162_rn(float2{a, b});
    return c.u;
}

// async global->LDS, 16B per lane (GEMM staging).
__device__ __forceinline__ void gload_lds16(const void* g, void* l) {
    __builtin_amdgcn_global_load_lds(
        (const __attribute__((address_space(1))) u32*)g,
        (__attribute__((address_space(3))) u32*)l, 16, 0, 0);
}

// All five f32->bf16 casts in one launch (region-dispatched by blockIdx).
__global__ void cast_all(const float* __restrict__ x,
                         const float* __restrict__ wq, const float* __restrict__ wk,
                         const float* __restrict__ wv, const float* __restrict__ wo,
                         u16* __restrict__ xb, u16* __restrict__ wqkvb, u16* __restrict__ wob) {
    int bi = blockIdx.x;
    const float* src; u16* dst; int local;
    if (bi < 8192)       { src = x;  dst = xb;               local = bi; }
    else if (bi < 9216)  { src = wq; dst = wqkvb;            local = bi - 8192; }
    else if (bi < 10240) { src = wk; dst = wqkvb + 1048576;  local = bi - 9216; }
    else if (bi < 11264) { src = wv; dst = wqkvb + 2097152;  local = bi - 10240; }
    else                 { src = wo; dst = wob;              local = bi - 11264; }
    int i = (local * 256 + (int)threadIdx.x) * 4;
    float4 v = *(const float4*)(src + i);
    ushort4 o; o.x = f2bf(v.x); o.y = f2bf(v.y); o.z = f2bf(v.z); o.w = f2bf(v.w);
    *(ushort4*)(dst + i) = o;
}

// C[m,n] = sum_k A[m,k] * B[n,k];  A:[M,K] bf16, B:[N,K] bf16 (both row-major)
// 1D grid, panel-swizzled: panels of 8 n-tiles x 64 m-tiles = 512 blocks
// (= the resident set) so co-resident blocks share one 4 MB B-panel + a
// compact A window in L2/LLC. Requires nTiles(N/128) % 8 == 0, M == 8192.
// ROPE_EN: apply RoPE to the fp32 accumulator in the epilogue for cols <
// 2048 (Q,K halves of QKV). Pairs (2i,2i+1) = adjacent c16 lanes; partner
// via __shfl_xor(v,1) (DPP quad-perm). Block-uniform branch (128 | 1024).
template<int CT_BF16, int ROPE_EN>
__global__ __launch_bounds__(256, 2)
void gemm_bt(const u16* __restrict__ A, const u16* __restrict__ Bm,
             void* __restrict__ Cp, const int* __restrict__ tp, int M, int N, int K) {
    __shared__ u16 As[128 * 32];
    __shared__ u16 Bs[128 * 32];
    const int tid = threadIdx.x;
    const int lane = tid & 63, wave = tid >> 6;
    const int bid = blockIdx.x;
    const int r9 = bid & 511;
    const int m0 = (r9 >> 3) * 128;
    const int n0 = (((bid >> 9) << 3) | (r9 & 7)) * 128;
    const int wm = (wave >> 1) * 64, wn = (wave & 1) * 64;
    const int q4 = lane >> 4, c16 = lane & 15;
    f32x4 acc[4][4] = {};

    for (int k0 = 0; k0 < K; k0 += 32) {
        #pragma unroll
        for (int j = 0; j < 2; ++j) {
            int off = wave * 2048 + j * 1024 + lane * 16;
            int row = off >> 6, cb = off & 63;
            gload_lds16(A + (size_t)(m0 + row) * K + k0 + (cb >> 1), (char*)As + off);
            gload_lds16(Bm + (size_t)(n0 + row) * K + k0 + (cb >> 1), (char*)Bs + off);
        }
        __syncthreads();
        bf16x8 af[4], bf[4];
        #pragma unroll
        for (int mt = 0; mt < 4; ++mt)
            af[mt] = *(const bf16x8*)&As[(wm + mt * 16 + c16) * 32 + q4 * 8];
        #pragma unroll
        for (int nt = 0; nt < 4; ++nt)
            bf[nt] = *(const bf16x8*)&Bs[(wn + nt * 16 + c16) * 32 + q4 * 8];
        #pragma unroll
        for (int mt = 0; mt < 4; ++mt)
            #pragma unroll
            for (int nt = 0; nt < 4; ++nt)
                acc[mt][nt] = __builtin_amdgcn_mfma_f32_16x16x32_bf16(af[mt], bf[nt], acc[mt][nt], 0, 0, 0);
        __syncthreads();
    }

    if (ROPE_EN && n0 < 2048) {
        // RoPE fused epilogue (Q/K halves). col = n0+wn+nt*16+c16;
        // i = (col&63)>>1 shared by the lane pair; s = row & 2047.
        const bool odd = (c16 & 1) != 0;
        float posf[4][4];
        #pragma unroll
        for (int mt = 0; mt < 4; ++mt)
            #pragma unroll
            for (int r = 0; r < 4; ++r)
                posf[mt][r] = (float)tp[(m0 + wm + mt * 16 + q4 * 4 + r) & (S_ - 1)];
        #pragma unroll
        for (int nt = 0; nt < 4; ++nt) {
            int col = n0 + wn + nt * 16 + c16;
            int fi = (col & 63) >> 1;
            float invf = __expf(-(float)fi * 0.2878231366242557f); // 10000^(-fi/32)
            #pragma unroll
            for (int mt = 0; mt < 4; ++mt)
                #pragma unroll
                for (int r = 0; r < 4; ++r) {
                    float v = acc[mt][nt][r];
                    float p = __shfl_xor(v, 1, 64);
                    float sn, cs;
                    sincosf(posf[mt][r] * invf, &sn, &cs);
                    float res = cs * v + (odd ? sn : -sn) * p;
                    int row = m0 + wm + mt * 16 + q4 * 4 + r;
                    ((u16*)Cp)[(size_t)row * N + col] = f2bf(res);
                }
        }
    } else {
        #pragma unroll
        for (int mt = 0; mt < 4; ++mt)
            #pragma unroll
            for (int nt = 0; nt < 4; ++nt)
                #pragma unroll
                for (int r = 0; r < 4; ++r) {
                    int row = m0 + wm + mt * 16 + q4 * 4 + r;
                    int col = n0 + wn + nt * 16 + c16;
                    float v = acc[mt][nt][r];
                    if (CT_BF16) ((u16*)Cp)[(size_t)row * N + col] = f2bf(v);
                    else         ((float*)Cp)[(size_t)row * N + col] = v;
                }
    }
}

// Balanced schedule: 12 groups per bh, each exactly 44 processes.
__device__ __constant__ signed char g_pairs[32] = {
    11,31, 12,30, 13,29, 14,28, 15,27, 16,26, 17,25, 18,24, 19,23, 20,22,
    10,21, 0,9,  7,8,  5,6,  3,4,  1,2 };
__device__ __constant__ unsigned char g_poff[13] = {0,1,2,3,4,5,6,7,8,9,10,12,16};

// FIXED-OFFSET softmax flash update (see round-7 notes): p = exp2(s*C - T),
// uniform scale cancels in O = (PV)/l. l_i per-lane partials, reduced in
// the epilogue.
__device__ __forceinline__ void attn_process(
    const u16* __restrict__ Kb, const u16* __restrict__ Vb, u16* __restrict__ Psw,
    const bf16x8 (&qf)[2], f32x4 (&of)[4], float& l_i,
    int qrow0, int kt, bool diag, int c16, int q4) {
    f32x4 sf[4] = {};
    #pragma unroll
    for (int kk = 0; kk < 2; ++kk)
        #pragma unroll
        for (int nt = 0; nt < 4; ++nt) {
            bf16x8 kf = *(const bf16x8*)&Kb[(nt * 16 + c16) * 72 + kk * 32 + q4 * 8];
            sf[nt] = __builtin_amdgcn_mfma_f32_16x16x32_bf16(kf, qf[kk], sf[nt], 0, 0, 0);
        }
    if (diag) {
        const int qg = qrow0 + c16;
        #pragma unroll
        for (int nt = 0; nt < 4; ++nt)
            #pragma unroll
            for (int r = 0; r < 4; ++r) {
                int kg = kt * 64 + nt * 16 + q4 * 4 + r;
                if (kg > qg) sf[nt][r] = -1e30f;
            }
    }
    const float C = 0.18033688011112042f;   // 0.125 * log2(e)
    const float T = 46.16624130844683f;     // 32 * log2(e)
    float rs = 0.f;
    #pragma unroll
    for (int nt = 0; nt < 4; ++nt) {
        float p0 = exp2f(__builtin_fmaf(sf[nt][0], C, -T));
        float p1 = exp2f(__builtin_fmaf(sf[nt][1], C, -T));
        float p2 = exp2f(__builtin_fmaf(sf[nt][2], C, -T));
        float p3 = exp2f(__builtin_fmaf(sf[nt][3], C, -T));
        rs += (p0 + p1) + (p2 + p3);
        uint2 w; w.x = pk2bf(p0, p1); w.y = pk2bf(p2, p3);
        *(uint2*)&Psw[c16 * 72 + nt * 16 + q4 * 4] = w;   // P[qrow][key]
    }
    l_i += rs;
    #pragma unroll
    for (int kk = 0; kk < 2; ++kk) {
        bf16x8 pf = *(const bf16x8*)&Psw[c16 * 72 + kk * 32 + q4 * 8];
        #pragma unroll
        for (int nt = 0; nt < 4; ++nt) {
            bf16x8 vf = *(const bf16x8*)&Vb[(nt * 16 + c16) * 72 + kk * 32 + q4 * 8];
            of[nt] = __builtin_amdgcn_mfma_f32_16x16x32_bf16(pf, vf, of[nt], 0, 0, 0);
        }
    }
}

// Flash attention: grid (12, 64) = 768 blocks = exactly 3/CU, one pass,
// 44 processes per block.
__global__ __launch_bounds__(256, 3)
void attn_kernel(const u16* __restrict__ QKV, u16* __restrict__ O) {
    __shared__ u16 Kt[2][64 * 72];    // [key][d], stride 72
    __shared__ u16 Vt[2][64 * 72];    // [d][key], stride 72
    __shared__ u16 Ps[4][16 * 72];    // per-wave P strip [qrow][key]
    __shared__ float aS[4][16];       // per-wave l redistribution (epilogue)
    const int tid = threadIdx.x, lane = tid & 63, wave = tid >> 6;
    const int q4 = lane >> 4, c16 = lane & 15;
    const int g = blockIdx.x;         // 0..11
    const int bh = blockIdx.y;
    const int b = bh >> 4, h = bh & 15;
    const size_t rowbase = (size_t)b * S_ * QKV_N;

    // K staging coords: thread covers 32B of one key row
    const int krow = tid >> 2, kcb = (tid & 3) * 16;
    const u16* kbase = QKV + rowbase + (size_t)krow * QKV_N + D_MODEL + h * 64 + kcb;
    // V staging coords: thread covers keys {2kp, 2kp+1} x 8 d's -> packed b32
    const int kp = tid & 31, dg = tid >> 5;   // dg 0..7
    const u16* vbase = QKV + rowbase + (size_t)(2 * kp) * QKV_N + 2 * D_MODEL + h * 64 + dg * 8;

    for (int pi = g_poff[g]; pi < g_poff[g + 1]; ++pi) {
        const int tA = g_pairs[2 * pi], tB = g_pairs[2 * pi + 1];

        bf16x8 qfA[2], qfB[2];
        {
            const u16* qa = QKV + rowbase + (size_t)(tA * 64 + wave * 16 + c16) * QKV_N + h * 64 + q4 * 8;
            qfA[0] = *(const bf16x8*)qa;
            qfA[1] = *(const bf16x8*)(qa + 32);
            const u16* qb = QKV + rowbase + (size_t)(tB * 64 + wave * 16 + c16) * QKV_N + h * 64 + q4 * 8;
            qfB[0] = *(const bf16x8*)qb;
            qfB[1] = *(const bf16x8*)(qb + 32);
        }
        f32x4 ofA[4] = {}, ofB[4] = {};
        float lA = 0.f, lB = 0.f;
        const int qrowA = tA * 64 + wave * 16;
        const int qrowB = tB * 64 + wave * 16;

        // prologue: stage tile 0 into buffer 0
        bf16x8 k0r, k1r, va, vb;
        k0r = *(const bf16x8*)kbase; k1r = *(const bf16x8*)(kbase + 8);
        va = *(const bf16x8*)vbase;  vb = *(const bf16x8*)(vbase + QKV_N);
        *(bf16x8*)&Kt[0][krow * 72 + kcb] = k0r;
        *(bf16x8*)&Kt[0][krow * 72 + kcb + 8] = k1r;
        #pragma unroll
        for (int j = 0; j < 8; ++j) {
            u32 w = ((u32)(u16)va[j]) | (((u32)(u16)vb[j]) << 16);
            *(u32*)&Vt[0][(dg * 8 + j) * 72 + 2 * kp] = w;
        }
        __syncthreads();

        int bb = 0;
        for (int kt = 0; kt <= tB; ++kt) {
            const bool more = kt < tB;
            if (more) {   // prefetch next tile into regs
                const u16* kp_ = kbase + (size_t)(kt + 1) * 64 * QKV_N;
                k0r = *(const bf16x8*)kp_; k1r = *(const bf16x8*)(kp_ + 8);
                const u16* vp_ = vbase + (size_t)(kt + 1) * 64 * QKV_N;
                va = *(const bf16x8*)vp_;  vb = *(const bf16x8*)(vp_ + QKV_N);
            }

            attn_process(Kt[bb], Vt[bb], Ps[wave], qfB, ofB, lB, qrowB, kt, kt == tB, c16, q4);

            if (more) {   // commit mid-iteration: vmcnt wait hides under process B
                *(bf16x8*)&Kt[bb ^ 1][krow * 72 + kcb] = k0r;
                *(bf16x8*)&Kt[bb ^ 1][krow * 72 + kcb + 8] = k1r;
                #pragma unroll
                for (int j = 0; j < 8; ++j) {
                    u32 w = ((u32)(u16)va[j]) | (((u32)(u16)vb[j]) << 16);
                    *(u32*)&Vt[bb ^ 1][(dg * 8 + j) * 72 + 2 * kp] = w;
                }
            }

            if (kt <= tA)
                attn_process(Kt[bb], Vt[bb], Ps[wave], qfA, ofA, lA, qrowA, kt, kt == tA, c16, q4);

            __syncthreads();
            bb ^= 1;
        }

        // epilogue: cross-lane l reduce (deferred), then redistribute to O rows
        lA += __shfl_xor(lA, 16, 64); lA += __shfl_xor(lA, 32, 64);
        lB += __shfl_xor(lB, 16, 64); lB += __shfl_xor(lB, 32, 64);
        if (q4 == 0) aS[wave][c16] = lA;
        f32x4 lv = *(const f32x4*)&aS[wave][q4 * 4];
        #pragma unroll
        for (int r = 0; r < 4; ++r) {
            float inv = 1.0f / lv[r];
            int row = b * S_ + tA * 64 + wave * 16 + q4 * 4 + r;
            #pragma unroll
            for (int nt = 0; nt < 4; ++nt)
                O[(size_t)row * D_MODEL + h * 64 + nt * 16 + c16] = f2bf(ofA[nt][r] * inv);
        }
        if (q4 == 0) aS[wave][c16] = lB;
        f32x4 lv2 = *(const f32x4*)&aS[wave][q4 * 4];
        #pragma unroll
        for (int r = 0; r < 4; ++r) {
            float inv = 1.0f / lv2[r];
            int row = b * S_ + tB * 64 + wave * 16 + q4 * 4 + r;
            #pragma unroll
            for (int nt = 0; nt < 4; ++nt)
                O[(size_t)row * D_MODEL + h * 64 + nt * 16 + c16] = f2bf(ofB[nt][r] * inv);
        }
    }
}

extern "C" void kernel_launch(void* const* d_in, const int* in_sizes, int n_in,
                              void* d_out, int out_size, void* d_ws, size_t ws_size,
                              hipStream_t stream) {
    const float* x  = (const float*)d_in[0];
    const int*   tp = (const int*)d_in[1];
    const float* Wq = (const float*)d_in[2];
    const float* Wk = (const float*)d_in[3];
    const float* Wv = (const float*)d_in[4];
    const float* Wo = (const float*)d_in[5];
    float* out = (float*)d_out;

    char* ws = (char*)d_ws;
    u16* xb    = (u16*)(ws);                 // 16,777,216 B
    u16* Wqkvb = (u16*)(ws + 16777216);      //  6,291,456 B
    u16* Wob   = (u16*)(ws + 23068672);      //  2,097,152 B
    u16* QKV   = (u16*)(ws + 25165824);      // 50,331,648 B
    u16* Ob    = (u16*)(ws + 75497472);      // 16,777,216 B  (total 92,274,688 B)

    cast_all<<<dim3(12288), dim3(256), 0, stream>>>(x, Wq, Wk, Wv, Wo, xb, Wqkvb, Wob);

    // QKV projection + fused RoPE (panel-swizzled 1D grid: 3 panels x 512)
    gemm_bt<1, 1><<<dim3(1536), dim3(256), 0, stream>>>(
        xb, Wqkvb, (void*)QKV, tp, ROWS, QKV_N, D_MODEL);

    attn_kernel<<<dim3(12, B_ * NHEAD), dim3(256), 0, stream>>>(QKV, Ob);

    // output projection (1 panel x 512)
    gemm_bt<0, 0><<<dim3(512), dim3(256), 0, stream>>>(
        Ob, Wob, (void*)out, nullptr, ROWS, D_MODEL, D_MODEL);
}

// Round 9
// 292.139 us; speedup vs baseline: 4.6909x; 4.6909x over previous
//
#include <hip/hip_runtime.h>
#include <hip/hip_bf16.h>

#define D_MODEL 1024
#define NHEAD 16
#define DK 64
#define B_ 4
#define S_ 2048
#define ROWS (B_*S_)          // 8192
#define QKV_N (3*D_MODEL)     // 3072

typedef __attribute__((ext_vector_type(4))) float f32x4;
typedef __attribute__((ext_vector_type(8))) short bf16x8;
typedef unsigned short u16;
typedef unsigned int u32;

__device__ __forceinline__ u16 f2bf(float f) {
    union { float f; u32 u; } x; x.f = f;
    u32 r = x.u + 0x7fffu + ((x.u >> 16) & 1u);
    return (u16)(r >> 16);
}
__device__ __forceinline__ float bf2f(u16 h) {
    union { u32 u; float f; } x; x.u = ((u32)h) << 16;
    return x.f;
}
__device__ __forceinline__ u32 pk2bf(float a, float b) {
    union { __hip_bfloat162 h; u32 u; } c;
    c.h = __float22bfloat162_rn(float2{a, b});
    return c.u;
}

// async global->LDS, 16B per lane (GEMM staging).
__device__ __forceinline__ void gload_lds16(const void* g, void* l) {
    __builtin_amdgcn_global_load_lds(
        (const __attribute__((address_space(1))) u32*)g,
        (__attribute__((address_space(3))) u32*)l, 16, 0, 0);
}

// All five f32->bf16 casts in one launch (region-dispatched by blockIdx).
__global__ void cast_all(const float* __restrict__ x,
                         const float* __restrict__ wq, const float* __restrict__ wk,
                         const float* __restrict__ wv, const float* __restrict__ wo,
                         u16* __restrict__ xb, u16* __restrict__ wqkvb, u16* __restrict__ wob) {
    int bi = blockIdx.x;
    const float* src; u16* dst; int local;
    if (bi < 8192)       { src = x;  dst = xb;               local = bi; }
    else if (bi < 9216)  { src = wq; dst = wqkvb;            local = bi - 8192; }
    else if (bi < 10240) { src = wk; dst = wqkvb + 1048576;  local = bi - 9216; }
    else if (bi < 11264) { src = wv; dst = wqkvb + 2097152;  local = bi - 10240; }
    else                 { src = wo; dst = wob;              local = bi - 11264; }
    int i = (local * 256 + (int)threadIdx.x) * 4;
    float4 v = *(const float4*)(src + i);
    ushort4 o; o.x = f2bf(v.x); o.y = f2bf(v.y); o.z = f2bf(v.z); o.w = f2bf(v.w);
    *(ushort4*)(dst + i) = o;
}

// RoPE cos/sin table: tab[s][fi] = (cos, sin)(pos[s] * 10000^(-fi/32)).
// Standalone kernel so the non-inlined OCML sincosf call (scratch, call ABI)
// cannot contaminate the GEMM's register allocation — in round 8 sincosf in
// the GEMM epilogue forced all 64 acc regs through scratch (3 GB/dispatch).
__global__ void rope_table(const int* __restrict__ tp, float2* __restrict__ tab) {
    int idx = blockIdx.x * 256 + (int)threadIdx.x;   // 65536 = 2048 * 32
    int s = idx >> 5, fi = idx & 31;
    float invf = __expf(-(float)fi * 0.2878231366242557f); // 10000^(-fi/32)
    float sn, cs;
    sincosf((float)tp[s] * invf, &sn, &cs);
    tab[idx] = make_float2(cs, sn);
}

// C[m,n] = sum_k A[m,k] * B[n,k];  A:[M,K] bf16, B:[N,K] bf16 (both row-major)
// 1D grid, panel-swizzled: panels of 8 n-tiles x 64 m-tiles = 512 blocks
// (= the resident set) so co-resident blocks share one B-panel + a compact
// A window in L2/LLC. ROPE_EN: table-based RoPE on the fp32 accumulator for
// cols < 2048 (Q,K). Pair partner via __shfl_xor(v,1); no transcendentals.
template<int CT_BF16, int ROPE_EN>
__global__ __launch_bounds__(256, 2)
void gemm_bt(const u16* __restrict__ A, const u16* __restrict__ Bm,
             void* __restrict__ Cp, const float2* __restrict__ tab, int M, int N, int K) {
    __shared__ u16 As[128 * 32];
    __shared__ u16 Bs[128 * 32];
    const int tid = threadIdx.x;
    const int lane = tid & 63, wave = tid >> 6;
    const int bid = blockIdx.x;
    const int r9 = bid & 511;
    const int m0 = (r9 >> 3) * 128;
    const int n0 = (((bid >> 9) << 3) | (r9 & 7)) * 128;
    const int wm = (wave >> 1) * 64, wn = (wave & 1) * 64;
    const int q4 = lane >> 4, c16 = lane & 15;
    f32x4 acc[4][4] = {};

    for (int k0 = 0; k0 < K; k0 += 32) {
        #pragma unroll
        for (int j = 0; j < 2; ++j) {
            int off = wave * 2048 + j * 1024 + lane * 16;
            int row = off >> 6, cb = off & 63;
            gload_lds16(A + (size_t)(m0 + row) * K + k0 + (cb >> 1), (char*)As + off);
            gload_lds16(Bm + (size_t)(n0 + row) * K + k0 + (cb >> 1), (char*)Bs + off);
        }
        __syncthreads();
        bf16x8 af[4], bf[4];
        #pragma unroll
        for (int mt = 0; mt < 4; ++mt)
            af[mt] = *(const bf16x8*)&As[(wm + mt * 16 + c16) * 32 + q4 * 8];
        #pragma unroll
        for (int nt = 0; nt < 4; ++nt)
            bf[nt] = *(const bf16x8*)&Bs[(wn + nt * 16 + c16) * 32 + q4 * 8];
        #pragma unroll
        for (int mt = 0; mt < 4; ++mt)
            #pragma unroll
            for (int nt = 0; nt < 4; ++nt)
                acc[mt][nt] = __builtin_amdgcn_mfma_f32_16x16x32_bf16(af[mt], bf[nt], acc[mt][nt], 0, 0, 0);
        __syncthreads();
    }

    if (ROPE_EN && n0 < 2048) {
        // RoPE fused epilogue (Q/K halves): res = cs*v -/+ sn*partner
        const bool odd = (c16 & 1) != 0;
        #pragma unroll
        for (int nt = 0; nt < 4; ++nt) {
            int col = n0 + wn + nt * 16 + c16;
            int fi = (col & 63) >> 1;
            #pragma unroll
            for (int mt = 0; mt < 4; ++mt)
                #pragma unroll
                for (int r = 0; r < 4; ++r) {
                    int row = m0 + wm + mt * 16 + q4 * 4 + r;
                    float v = acc[mt][nt][r];
                    float p = __shfl_xor(v, 1, 64);
                    float2 t = tab[(row & (S_ - 1)) * 32 + fi];
                    float res = t.x * v + (odd ? t.y : -t.y) * p;
                    ((u16*)Cp)[(size_t)row * N + col] = f2bf(res);
                }
        }
    } else {
        #pragma unroll
        for (int mt = 0; mt < 4; ++mt)
            #pragma unroll
            for (int nt = 0; nt < 4; ++nt)
                #pragma unroll
                for (int r = 0; r < 4; ++r) {
                    int row = m0 + wm + mt * 16 + q4 * 4 + r;
                    int col = n0 + wn + nt * 16 + c16;
                    float v = acc[mt][nt][r];
                    if (CT_BF16) ((u16*)Cp)[(size_t)row * N + col] = f2bf(v);
                    else         ((float*)Cp)[(size_t)row * N + col] = v;
                }
    }
}

// Balanced schedule: 12 groups per bh, each exactly 44 processes.
__device__ __constant__ signed char g_pairs[32] = {
    11,31, 12,30, 13,29, 14,28, 15,27, 16,26, 17,25, 18,24, 19,23, 20,22,
    10,21, 0,9,  7,8,  5,6,  3,4,  1,2 };
__device__ __constant__ unsigned char g_poff[13] = {0,1,2,3,4,5,6,7,8,9,10,12,16};

// FIXED-OFFSET softmax flash update: p = exp2(s*C - T); uniform scale
// cancels in O = (PV)/l. l_i per-lane partials, reduced in the epilogue.
__device__ __forceinline__ void attn_process(
    const u16* __restrict__ Kb, const u16* __restrict__ Vb, u16* __restrict__ Psw,
    const bf16x8 (&qf)[2], f32x4 (&of)[4], float& l_i,
    int qrow0, int kt, bool diag, int c16, int q4) {
    f32x4 sf[4] = {};
    #pragma unroll
    for (int kk = 0; kk < 2; ++kk)
        #pragma unroll
        for (int nt = 0; nt < 4; ++nt) {
            bf16x8 kf = *(const bf16x8*)&Kb[(nt * 16 + c16) * 72 + kk * 32 + q4 * 8];
            sf[nt] = __builtin_amdgcn_mfma_f32_16x16x32_bf16(kf, qf[kk], sf[nt], 0, 0, 0);
        }
    if (diag) {
        const int qg = qrow0 + c16;
        #pragma unroll
        for (int nt = 0; nt < 4; ++nt)
            #pragma unroll
            for (int r = 0; r < 4; ++r) {
                int kg = kt * 64 + nt * 16 + q4 * 4 + r;
                if (kg > qg) sf[nt][r] = -1e30f;
            }
    }
    const float C = 0.18033688011112042f;   // 0.125 * log2(e)
    const float T = 46.16624130844683f;     // 32 * log2(e)
    float rs = 0.f;
    #pragma unroll
    for (int nt = 0; nt < 4; ++nt) {
        float p0 = exp2f(__builtin_fmaf(sf[nt][0], C, -T));
        float p1 = exp2f(__builtin_fmaf(sf[nt][1], C, -T));
        float p2 = exp2f(__builtin_fmaf(sf[nt][2], C, -T));
        float p3 = exp2f(__builtin_fmaf(sf[nt][3], C, -T));
        rs += (p0 + p1) + (p2 + p3);
        uint2 w; w.x = pk2bf(p0, p1); w.y = pk2bf(p2, p3);
        *(uint2*)&Psw[c16 * 72 + nt * 16 + q4 * 4] = w;   // P[qrow][key]
    }
    l_i += rs;
    #pragma unroll
    for (int kk = 0; kk < 2; ++kk) {
        bf16x8 pf = *(const bf16x8*)&Psw[c16 * 72 + kk * 32 + q4 * 8];
        #pragma unroll
        for (int nt = 0; nt < 4; ++nt) {
            bf16x8 vf = *(const bf16x8*)&Vb[(nt * 16 + c16) * 72 + kk * 32 + q4 * 8];
            of[nt] = __builtin_amdgcn_mfma_f32_16x16x32_bf16(pf, vf, of[nt], 0, 0, 0);
        }
    }
}

// Flash attention: grid (12, 64) = 768 blocks = exactly 3/CU, one pass,
// 44 processes per block.
__global__ __launch_bounds__(256, 3)
void attn_kernel(const u16* __restrict__ QKV, u16* __restrict__ O) {
    __shared__ u16 Kt[2][64 * 72];    // [key][d], stride 72
    __shared__ u16 Vt[2][64 * 72];    // [d][key], stride 72
    __shared__ u16 Ps[4][16 * 72];    // per-wave P strip [qrow][key]
    __shared__ float aS[4][16];       // per-wave l redistribution (epilogue)
    const int tid = threadIdx.x, lane = tid & 63, wave = tid >> 6;
    const int q4 = lane >> 4, c16 = lane & 15;
    const int g = blockIdx.x;         // 0..11
    const int bh = blockIdx.y;
    const int b = bh >> 4, h = bh & 15;
    const size_t rowbase = (size_t)b * S_ * QKV_N;

    // K staging coords: thread covers 32B of one key row
    const int krow = tid >> 2, kcb = (tid & 3) * 16;
    const u16* kbase = QKV + rowbase + (size_t)krow * QKV_N + D_MODEL + h * 64 + kcb;
    // V staging coords: thread covers keys {2kp, 2kp+1} x 8 d's -> packed b32
    const int kp = tid & 31, dg = tid >> 5;   // dg 0..7
    const u16* vbase = QKV + rowbase + (size_t)(2 * kp) * QKV_N + 2 * D_MODEL + h * 64 + dg * 8;

    for (int pi = g_poff[g]; pi < g_poff[g + 1]; ++pi) {
        const int tA = g_pairs[2 * pi], tB = g_pairs[2 * pi + 1];

        bf16x8 qfA[2], qfB[2];
        {
            const u16* qa = QKV + rowbase + (size_t)(tA * 64 + wave * 16 + c16) * QKV_N + h * 64 + q4 * 8;
            qfA[0] = *(const bf16x8*)qa;
            qfA[1] = *(const bf16x8*)(qa + 32);
            const u16* qb = QKV + rowbase + (size_t)(tB * 64 + wave * 16 + c16) * QKV_N + h * 64 + q4 * 8;
            qfB[0] = *(const bf16x8*)qb;
            qfB[1] = *(const bf16x8*)(qb + 32);
        }
        f32x4 ofA[4] = {}, ofB[4] = {};
        float lA = 0.f, lB = 0.f;
        const int qrowA = tA * 64 + wave * 16;
        const int qrowB = tB * 64 + wave * 16;

        // prologue: stage tile 0 into buffer 0
        bf16x8 k0r, k1r, va, vb;
        k0r = *(const bf16x8*)kbase; k1r = *(const bf16x8*)(kbase + 8);
        va = *(const bf16x8*)vbase;  vb = *(const bf16x8*)(vbase + QKV_N);
        *(bf16x8*)&Kt[0][krow * 72 + kcb] = k0r;
        *(bf16x8*)&Kt[0][krow * 72 + kcb + 8] = k1r;
        #pragma unroll
        for (int j = 0; j < 8; ++j) {
            u32 w = ((u32)(u16)va[j]) | (((u32)(u16)vb[j]) << 16);
            *(u32*)&Vt[0][(dg * 8 + j) * 72 + 2 * kp] = w;
        }
        __syncthreads();

        int bb = 0;
        for (int kt = 0; kt <= tB; ++kt) {
            const bool more = kt < tB;
            if (more) {   // prefetch next tile into regs
                const u16* kp_ = kbase + (size_t)(kt + 1) * 64 * QKV_N;
                k0r = *(const bf16x8*)kp_; k1r = *(const bf16x8*)(kp_ + 8);
                const u16* vp_ = vbase + (size_t)(kt + 1) * 64 * QKV_N;
                va = *(const bf16x8*)vp_;  vb = *(const bf16x8*)(vp_ + QKV_N);
            }

            attn_process(Kt[bb], Vt[bb], Ps[wave], qfB, ofB, lB, qrowB, kt, kt == tB, c16, q4);

            if (more) {   // commit mid-iteration: vmcnt wait hides under process B
                *(bf16x8*)&Kt[bb ^ 1][krow * 72 + kcb] = k0r;
                *(bf16x8*)&Kt[bb ^ 1][krow * 72 + kcb + 8] = k1r;
                #pragma unroll
                for (int j = 0; j < 8; ++j) {
                    u32 w = ((u32)(u16)va[j]) | (((u32)(u16)vb[j]) << 16);
                    *(u32*)&Vt[bb ^ 1][(dg * 8 + j) * 72 + 2 * kp] = w;
                }
            }

            if (kt <= tA)
                attn_process(Kt[bb], Vt[bb], Ps[wave], qfA, ofA, lA, qrowA, kt, kt == tA, c16, q4);

            __syncthreads();
            bb ^= 1;
        }

        // epilogue: cross-lane l reduce (deferred), then redistribute to O rows
        lA += __shfl_xor(lA, 16, 64); lA += __shfl_xor(lA, 32, 64);
        lB += __shfl_xor(lB, 16, 64); lB += __shfl_xor(lB, 32, 64);
        if (q4 == 0) aS[wave][c16] = lA;
        f32x4 lv = *(const f32x4*)&aS[wave][q4 * 4];
        #pragma unroll
        for (int r = 0; r < 4; ++r) {
            float inv = 1.0f / lv[r];
            int row = b * S_ + tA * 64 + wave * 16 + q4 * 4 + r;
            #pragma unroll
            for (int nt = 0; nt < 4; ++nt)
                O[(size_t)row * D_MODEL + h * 64 + nt * 16 + c16] = f2bf(ofA[nt][r] * inv);
        }
        if (q4 == 0) aS[wave][c16] = lB;
        f32x4 lv2 = *(const f32x4*)&aS[wave][q4 * 4];
        #pragma unroll
        for (int r = 0; r < 4; ++r) {
            float inv = 1.0f / lv2[r];
            int row = b * S_ + tB * 64 + wave * 16 + q4 * 4 + r;
            #pragma unroll
            for (int nt = 0; nt < 4; ++nt)
                O[(size_t)row * D_MODEL + h * 64 + nt * 16 + c16] = f2bf(ofB[nt][r] * inv);
        }
    }
}

extern "C" void kernel_launch(void* const* d_in, const int* in_sizes, int n_in,
                              void* d_out, int out_size, void* d_ws, size_t ws_size,
                              hipStream_t stream) {
    const float* x  = (const float*)d_in[0];
    const int*   tp = (const int*)d_in[1];
    const float* Wq = (const float*)d_in[2];
    const float* Wk = (const float*)d_in[3];
    const float* Wv = (const float*)d_in[4];
    const float* Wo = (const float*)d_in[5];
    float* out = (float*)d_out;

    char* ws = (char*)d_ws;
    u16* xb    = (u16*)(ws);                 // 16,777,216 B
    u16* Wqkvb = (u16*)(ws + 16777216);      //  6,291,456 B
    u16* Wob   = (u16*)(ws + 23068672);      //  2,097,152 B
    u16* QKV   = (u16*)(ws + 25165824);      // 50,331,648 B
    u16* Ob    = (u16*)(ws + 75497472);      // 16,777,216 B  (total 92,274,688 B)
    // RoPE table aliases the FRONT of Ob: it is consumed by the QKV GEMM,
    // which completes before attn_kernel writes Ob (same-stream ordering).
    float2* tab = (float2*)Ob;               // 524,288 B

    cast_all<<<dim3(12288), dim3(256), 0, stream>>>(x, Wq, Wk, Wv, Wo, xb, Wqkvb, Wob);
    rope_table<<<dim3(256), dim3(256), 0, stream>>>(tp, tab);

    // QKV projection + fused table-RoPE (panel-swizzled 1D grid: 3 panels x 512)
    gemm_bt<1, 1><<<dim3(1536), dim3(256), 0, stream>>>(
        xb, Wqkvb, (void*)QKV, tab, ROWS, QKV_N, D_MODEL);

    attn_kernel<<<dim3(12, B_ * NHEAD), dim3(256), 0, stream>>>(QKV, Ob);

    // output projection (1 panel x 512)
    gemm_bt<0, 0><<<dim3(512), dim3(256), 0, stream>>>(
        Ob, Wob, (void*)out, nullptr, ROWS, D_MODEL, D_MODEL);
}